// Round 4
// baseline (153.062 us; speedup 1.0000x reference)
//
#include <hip/hip_runtime.h>

// FCN_81913616269760: 3-layer tanh RNN, B=256, T=16384, IN=1, H=16, OUT=1.
// Round 13: SEG_LEN 128 -> 64 (4096 waves = 4/SIMD). r12 counters: VALU
// 66% + MFMA + ~25% dependency bubbles at 2 waves/SIMD (both waves stall
// together in the exp2->rcp tanh latency chain). 4 waves/SIMD fills the
// bubbles; +20% warmup work (32/96 vs 32/160) is outweighed if VALUBusy
// reaches ~85%. No accuracy change (WARMUP stays 32).
//   Register-resident recurrence via MFMA K-slot permutation (r11):
//   sigma(8q+i) = {plane0 row 4q+i (i<4); plane1 row 4q+i-4 (i>=4)} applied
//   to both A (loaded once) and B makes each lane's B fragment exactly the
//   4 values it just computed:
//     B4 = [hi(own h0 rows) ; lo(own h0 rows)]
//     B1 = [hi(own h0 rows) ; hi(own h1 rows)]
//   -> zero LDS, zero barriers, x chunk-prefetched to registers, y stored
//   straight from q==0 lanes.
// Per step: 5 MFMAs, 9 tanh, ~10 pack VALU, 4 FMA; no LDS ops.

#define T_LEN 16384
#define NBATCH 256
#define HDIM 16
#define SEG_LEN 64
#define WARMUP 32
#define NSEG (T_LEN / SEG_LEN)  // 256
#define KSC 2.88539008177793f   // 2*log2(e): tanh(s)=1-2/(exp2(K*s)+1)

typedef __attribute__((ext_vector_type(8))) short short8;   // bf16x8 A/B frag
typedef __attribute__((ext_vector_type(4))) float float4v;  // f32x4 C/D frag
typedef __attribute__((ext_vector_type(4))) unsigned int uint4v;

#define MFMA(a, b, c) __builtin_amdgcn_mfma_f32_16x16x32_bf16(a, b, c, 0, 0, 0)

__device__ __forceinline__ float tanh_pre(float s) {
  // weights/biases pre-scaled by KSC: tanh = 1 - 2/(exp2(s)+1)
  float e = __builtin_amdgcn_exp2f(s);
  float r = __builtin_amdgcn_rcpf(e + 1.0f);
  return __builtin_fmaf(-2.0f, r, 1.0f);
}

__device__ __forceinline__ short bf16hi(float v) {
  return (short)(__float_as_uint(v) >> 16);  // truncated bf16
}

// pack 4 truncated-bf16 hi halves of f32x4 into 2 dwords (2 v_perm)
__device__ __forceinline__ uint2 pack_hi(float4v d) {
  uint2 p;
  p.x = __builtin_amdgcn_perm(__float_as_uint(d[1]), __float_as_uint(d[0]),
                              0x07060302u);
  p.y = __builtin_amdgcn_perm(__float_as_uint(d[3]), __float_as_uint(d[2]),
                              0x07060302u);
  return p;
}

// pack exact bf16 residuals (lo plane) of f32x4 into 2 dwords
__device__ __forceinline__ uint2 pack_lo(float4v d) {
  float l0 = d[0] - __uint_as_float(__float_as_uint(d[0]) & 0xFFFF0000u);
  float l1 = d[1] - __uint_as_float(__float_as_uint(d[1]) & 0xFFFF0000u);
  float l2 = d[2] - __uint_as_float(__float_as_uint(d[2]) & 0xFFFF0000u);
  float l3 = d[3] - __uint_as_float(__float_as_uint(d[3]) & 0xFFFF0000u);
  uint2 p;
  p.x = __builtin_amdgcn_perm(__float_as_uint(l1), __float_as_uint(l0),
                              0x07060302u);
  p.y = __builtin_amdgcn_perm(__float_as_uint(l3), __float_as_uint(l2),
                              0x07060302u);
  return p;
}

__device__ __forceinline__ uint4v mk4(uint2 a, uint2 b) {
  uint4v t;
  t[0] = a.x;
  t[1] = a.y;
  t[2] = b.x;
  t[3] = b.y;
  return t;
}

__device__ __forceinline__ short8 as_s8(uint4v u) {
  union {
    uint4v u;
    short8 s;
  } c;
  c.u = u;
  return c.s;
}

__global__ __launch_bounds__(256, 4) void rnn3_kernel(
    const float* __restrict__ x, const float* __restrict__ prev_h0,
    const float* __restrict__ post_h0, const float* __restrict__ Wih0,
    const float* __restrict__ Whh0, const float* __restrict__ bih0,
    const float* __restrict__ bhh0, const float* __restrict__ Wih1,
    const float* __restrict__ Whh1, const float* __restrict__ bih1,
    const float* __restrict__ bhh1, const float* __restrict__ Wihp,
    const float* __restrict__ Whhp, const float* __restrict__ bihp,
    const float* __restrict__ bhhp, float* __restrict__ out) {
  const int lane = threadIdx.x & 63;
  const int wave = threadIdx.x >> 6;  // [0,4)
  const int b = lane & 15;            // MFMA col (batch) / A row j
  const int q = lane >> 4;            // quad: D rows q*4..q*4+3; k-slots 8q..
  const int bg = blockIdx.x >> 6;                   // batch group [0,16)
  const int seg = ((blockIdx.x & 63) << 2) | wave;  // segment [0,256)
  const int batch = bg * 16 + b;

  const int t0 = (seg == 0) ? 0 : seg * SEG_LEN - WARMUP;
  const int trip = (seg == 0) ? SEG_LEN : SEG_LEN + WARMUP;
  const int wchunks = (seg == 0) ? 0 : WARMUP / 16;

  // --- A fragments under sigma: slot 8q+i consumes
  //     i<4: plane0 value of h-row 4q+i ; i>=4: plane1 value of row 4q+i-4
  short8 A1h, A1l, A4h, A5l, Ap;
#pragma unroll
  for (int i = 0; i < 8; ++i) {
    const int r = 4 * q + (i & 3);  // h row this slot consumes
    // layer1: plane0 = h0hi -> Wih1, plane1 = h1hi -> Whh1
    const float* s1 = (i < 4) ? Wih1 : Whh1;
    float w1 = KSC * s1[b * HDIM + r];
    unsigned hb = __float_as_uint(w1) & 0xFFFF0000u;
    A1h[i] = (short)(hb >> 16);
    A1l[i] = bf16hi(w1 - __uint_as_float(hb));
    // layer0: plane0 = h0hi, plane1 = h0lo; Whh0hi on both, Whh0lo on plane0
    float w0 = KSC * Whh0[b * HDIM + r];
    unsigned hb0 = __float_as_uint(w0) & 0xFFFF0000u;
    A4h[i] = (short)(hb0 >> 16);
    A5l[i] = (i < 4) ? bf16hi(w0 - __uint_as_float(hb0)) : (short)0;
    // post-layer A: row 0 only, h1 plane only (i>=4)
    float wpv = (b == 0 && i >= 4) ? KSC * Wihp[r] : 0.0f;
    Ap[i] = bf16hi(wpv);
  }

  // --- per-row constants (rows q*4..q*4+3), all KSC-scaled ---
  float4v c1v, c0pv, a0pv;
#pragma unroll
  for (int r = 0; r < 4; ++r) {
    const int row = q * 4 + r;
    c1v[r] = KSC * (bih1[row] + bhh1[row]);
    float a0w = Wih0[row];  // IN=1: Wih0 is (16,1)
    a0pv[r] = KSC * 0.5f * a0w;
    c0pv[r] = KSC * __builtin_fmaf(0.5f, a0w, bih0[row] + bhh0[row]);
  }
  const float whp = KSC * Whhp[0];
  float4v cpv = {0.f, 0.f, 0.f, 0.f};
  cpv[0] = (q == 0) ? KSC * (bihp[0] + bhhp[0]) : 0.0f;

  float yv = post_h0[0];
  float yw[16];
#pragma unroll
  for (int s = 0; s < 16; ++s) yw[s] = 0.0f;

  const float* xp = x + (size_t)batch * T_LEN + t0;
  float* ob = out + (size_t)batch * T_LEN + t0;

  // --- init states straight into register B fragments ---
  uint4v B4, B1;
  {
    float4v h0i, h1i;
#pragma unroll
    for (int r = 0; r < 4; ++r) {
      h0i[r] = prev_h0[q * 4 + r];
      h1i[r] = prev_h0[HDIM + q * 4 + r];
    }
    uint2 h0h = pack_hi(h0i);
    uint2 h0l = pack_lo(h0i);
    uint2 h1h = pack_hi(h1i);
    B4 = mk4(h0h, h0l);
    B1 = mk4(h0h, h1h);
  }

  const int NC = trip / 16;
  // x chunk prefetch: each lane loads its own batch's 16 x values
  float4v xA = *(const float4v*)(xp);
  float4v xB = *(const float4v*)(xp + 4);
  float4v xC = *(const float4v*)(xp + 8);
  float4v xD = *(const float4v*)(xp + 12);

  for (int c = 0; c < NC; ++c) {
    float4v x0_ = xA, x1_ = xB, x2_ = xC, x3_ = xD;
    if (c + 1 < NC) {
      const float* xn = xp + (c + 1) * 16;
      xA = *(const float4v*)(xn);
      xB = *(const float4v*)(xn + 4);
      xC = *(const float4v*)(xn + 8);
      xD = *(const float4v*)(xn + 12);
    }

#pragma unroll
    for (int i = 0; i < 16; ++i) {
      // flush chunk c-1's y (slots complete after (c, i=1))
      if (i == 2) {
        if (c > wchunks && q == 0) {
#pragma unroll
          for (int r = 0; r < 4; ++r) {
            float4v v = {yw[r * 4], yw[r * 4 + 1], yw[r * 4 + 2],
                         yw[r * 4 + 3]};
            *(float4v*)(ob + (c - 1) * 16 + r * 4) = v;
          }
        }
      }

      const bool first = (c == 0 && i == 0);
      float xcur = (i < 4)    ? x0_[i & 3]
                   : (i < 8)  ? x1_[i & 3]
                   : (i < 12) ? x2_[i & 3]
                              : x3_[i & 3];
      float4v cx;
#pragma unroll
      for (int r = 0; r < 4; ++r)
        cx[r] = __builtin_fmaf(a0pv[r], xcur, c0pv[r]);

      // 5 MFMAs off B1/B4 = [h0_{t-1}; h1_{t-2}] planes (skewed pipeline)
      short8 B1s = as_s8(B1);
      short8 B4s = as_s8(B4);
      float4v d1 = MFMA(A1h, B1s, c1v);  // W1hi . h(bf16)
      d1 = MFMA(A1l, B1s, d1);           // + W1lo . h
      float4v dp = MFMA(Ap, B1s, cpv);   // row0: wp . h1_{t-2} + cp
      float4v d0 = MFMA(A4h, B4s, cx);   // W0hi.(h0hi+h0lo) + bias + x
      d0 = MFMA(A5l, B4s, d0);           // + W0lo.h0hi

      float4v hn1, hn0;
#pragma unroll
      for (int r = 0; r < 4; ++r) {
        hn1[r] = tanh_pre(d1[r]);  // h1_{t-1}
        hn0[r] = tanh_pre(d0[r]);  // h0_t
      }

      // y_{t-2} on q==0 lanes (garbage elsewhere, harmless)
      float yn = tanh_pre(__builtin_fmaf(whp, yv, dp[0]));
      if (i >= 2) {
        yv = yn;
      } else {
        if (c > 0) yv = yn;  // t<2: keep init y
      }
      yw[(i + 14) & 15] = yv;

      // next-step B fragments built entirely in-lane (sigma layout)
      uint2 h0h = pack_hi(hn0);
      uint2 h0l = pack_lo(hn0);
      B4 = mk4(h0h, h0l);
      if (!first) {
        uint2 h1h = pack_hi(hn1);
        B1 = mk4(h0h, h1h);
      } else {
        B1[0] = h0h.x;  // h1 half keeps init at t=0
        B1[1] = h0h.y;
      }
    }
  }

  // --- drain: y_{trip-2}, y_{trip-1}, then flush last chunk ---
  {
    // B1 = [h0_{trip-1}; h1_{trip-2}]
    short8 B1s = as_s8(B1);
    float4v d1 = MFMA(A1h, B1s, c1v);
    d1 = MFMA(A1l, B1s, d1);
    float4v dp = MFMA(Ap, B1s, cpv);
    float4v hn1;
#pragma unroll
    for (int r = 0; r < 4; ++r) hn1[r] = tanh_pre(d1[r]);  // h1_{trip-1}
    yv = tanh_pre(__builtin_fmaf(whp, yv, dp[0]));         // y_{trip-2}
    yw[14] = yv;
    uint2 h1h = pack_hi(hn1);
    B1[2] = h1h.x;
    B1[3] = h1h.y;
    B1s = as_s8(B1);
    dp = MFMA(Ap, B1s, cpv);
    yv = tanh_pre(__builtin_fmaf(whp, yv, dp[0]));  // y_{trip-1}
    yw[15] = yv;
    if (q == 0) {
#pragma unroll
      for (int r = 0; r < 4; ++r) {
        float4v v = {yw[r * 4], yw[r * 4 + 1], yw[r * 4 + 2], yw[r * 4 + 3]};
        *(float4v*)(ob + (NC - 1) * 16 + r * 4) = v;
      }
    }
  }
}

extern "C" void kernel_launch(void* const* d_in, const int* in_sizes, int n_in,
                              void* d_out, int out_size, void* d_ws,
                              size_t ws_size, hipStream_t stream) {
  const float* x = (const float*)d_in[0];
  const float* prev_h0 = (const float*)d_in[1];
  const float* post_h0 = (const float*)d_in[2];
  const float* Wih0 = (const float*)d_in[3];
  const float* Whh0 = (const float*)d_in[4];
  const float* bih0 = (const float*)d_in[5];
  const float* bhh0 = (const float*)d_in[6];
  const float* Wih1 = (const float*)d_in[7];
  const float* Whh1 = (const float*)d_in[8];
  const float* bih1 = (const float*)d_in[9];
  const float* bhh1 = (const float*)d_in[10];
  const float* Wihp = (const float*)d_in[11];
  const float* Whhp = (const float*)d_in[12];
  const float* bihp = (const float*)d_in[13];
  const float* bhhp = (const float*)d_in[14];
  float* out = (float*)d_out;

  // 16 batch-groups x 64 segment-quads = 1024 blocks x 256 threads
  // = 4096 waves = 4 waves/SIMD (4 blocks/CU, 0 LDS)
  rnn3_kernel<<<dim3(1024), dim3(256), 0, stream>>>(
      x, prev_h0, post_h0, Wih0, Whh0, bih0, bhh0, Wih1, Whh1, bih1, bhh1,
      Wihp, Whhp, bihp, bhhp, out);
}

// Round 5
// 139.832 us; speedup vs baseline: 1.0946x; 1.0946x over previous
//
#include <hip/hip_runtime.h>

// FCN_81913616269760: 3-layer tanh RNN, B=256, T=16384, IN=1, H=16, OUT=1.
// Round 14: revert SEG to 128 (r13 showed 2->4 waves/SIMD buys only 3.5%
// efficiency -- machine is throughput-bound at ~322 VALU-cyc/step, TLP is
// a dead lever) and cut WARMUP 32 -> 16. Convergence: h-chain 0.49^16 ~
// 1e-5, y-chain 0.6^16 ~ 3e-4, both << bf16 state floor (absmax 0.0176).
// Steps/wave 160 -> 144 (-10%).
//   Register-resident recurrence via MFMA K-slot permutation (r11):
//   sigma(8q+i) = {plane0 row 4q+i (i<4); plane1 row 4q+i-4 (i>=4)} applied
//   to both A (loaded once) and B makes each lane's B fragment exactly the
//   4 values it just computed:
//     B4 = [hi(own h0 rows) ; lo(own h0 rows)]
//     B1 = [hi(own h0 rows) ; hi(own h1 rows)]
//   -> zero LDS, zero barriers, x chunk-prefetched to registers, y stored
//   straight from q==0 lanes.
// Per step: 5 MFMAs, 9 tanh, ~10 pack VALU, 4 FMA; no LDS ops.

#define T_LEN 16384
#define NBATCH 256
#define HDIM 16
#define SEG_LEN 128
#define WARMUP 16
#define NSEG (T_LEN / SEG_LEN)  // 128
#define KSC 2.88539008177793f   // 2*log2(e): tanh(s)=1-2/(exp2(K*s)+1)

typedef __attribute__((ext_vector_type(8))) short short8;   // bf16x8 A/B frag
typedef __attribute__((ext_vector_type(4))) float float4v;  // f32x4 C/D frag
typedef __attribute__((ext_vector_type(4))) unsigned int uint4v;

#define MFMA(a, b, c) __builtin_amdgcn_mfma_f32_16x16x32_bf16(a, b, c, 0, 0, 0)

__device__ __forceinline__ float tanh_pre(float s) {
  // weights/biases pre-scaled by KSC: tanh = 1 - 2/(exp2(s)+1)
  float e = __builtin_amdgcn_exp2f(s);
  float r = __builtin_amdgcn_rcpf(e + 1.0f);
  return __builtin_fmaf(-2.0f, r, 1.0f);
}

__device__ __forceinline__ short bf16hi(float v) {
  return (short)(__float_as_uint(v) >> 16);  // truncated bf16
}

// pack 4 truncated-bf16 hi halves of f32x4 into 2 dwords (2 v_perm)
__device__ __forceinline__ uint2 pack_hi(float4v d) {
  uint2 p;
  p.x = __builtin_amdgcn_perm(__float_as_uint(d[1]), __float_as_uint(d[0]),
                              0x07060302u);
  p.y = __builtin_amdgcn_perm(__float_as_uint(d[3]), __float_as_uint(d[2]),
                              0x07060302u);
  return p;
}

// pack exact bf16 residuals (lo plane) of f32x4 into 2 dwords
__device__ __forceinline__ uint2 pack_lo(float4v d) {
  float l0 = d[0] - __uint_as_float(__float_as_uint(d[0]) & 0xFFFF0000u);
  float l1 = d[1] - __uint_as_float(__float_as_uint(d[1]) & 0xFFFF0000u);
  float l2 = d[2] - __uint_as_float(__float_as_uint(d[2]) & 0xFFFF0000u);
  float l3 = d[3] - __uint_as_float(__float_as_uint(d[3]) & 0xFFFF0000u);
  uint2 p;
  p.x = __builtin_amdgcn_perm(__float_as_uint(l1), __float_as_uint(l0),
                              0x07060302u);
  p.y = __builtin_amdgcn_perm(__float_as_uint(l3), __float_as_uint(l2),
                              0x07060302u);
  return p;
}

__device__ __forceinline__ uint4v mk4(uint2 a, uint2 b) {
  uint4v t;
  t[0] = a.x;
  t[1] = a.y;
  t[2] = b.x;
  t[3] = b.y;
  return t;
}

__device__ __forceinline__ short8 as_s8(uint4v u) {
  union {
    uint4v u;
    short8 s;
  } c;
  c.u = u;
  return c.s;
}

__global__ __launch_bounds__(256, 2) void rnn3_kernel(
    const float* __restrict__ x, const float* __restrict__ prev_h0,
    const float* __restrict__ post_h0, const float* __restrict__ Wih0,
    const float* __restrict__ Whh0, const float* __restrict__ bih0,
    const float* __restrict__ bhh0, const float* __restrict__ Wih1,
    const float* __restrict__ Whh1, const float* __restrict__ bih1,
    const float* __restrict__ bhh1, const float* __restrict__ Wihp,
    const float* __restrict__ Whhp, const float* __restrict__ bihp,
    const float* __restrict__ bhhp, float* __restrict__ out) {
  const int lane = threadIdx.x & 63;
  const int wave = threadIdx.x >> 6;  // [0,4)
  const int b = lane & 15;            // MFMA col (batch) / A row j
  const int q = lane >> 4;            // quad: D rows q*4..q*4+3; k-slots 8q..
  const int bg = blockIdx.x >> 5;                   // batch group [0,16)
  const int seg = ((blockIdx.x & 31) << 2) | wave;  // segment [0,128)
  const int batch = bg * 16 + b;

  const int t0 = (seg == 0) ? 0 : seg * SEG_LEN - WARMUP;
  const int trip = (seg == 0) ? SEG_LEN : SEG_LEN + WARMUP;
  const int wchunks = (seg == 0) ? 0 : WARMUP / 16;

  // --- A fragments under sigma: slot 8q+i consumes
  //     i<4: plane0 value of h-row 4q+i ; i>=4: plane1 value of row 4q+i-4
  short8 A1h, A1l, A4h, A5l, Ap;
#pragma unroll
  for (int i = 0; i < 8; ++i) {
    const int r = 4 * q + (i & 3);  // h row this slot consumes
    // layer1: plane0 = h0hi -> Wih1, plane1 = h1hi -> Whh1
    const float* s1 = (i < 4) ? Wih1 : Whh1;
    float w1 = KSC * s1[b * HDIM + r];
    unsigned hb = __float_as_uint(w1) & 0xFFFF0000u;
    A1h[i] = (short)(hb >> 16);
    A1l[i] = bf16hi(w1 - __uint_as_float(hb));
    // layer0: plane0 = h0hi, plane1 = h0lo; Whh0hi on both, Whh0lo on plane0
    float w0 = KSC * Whh0[b * HDIM + r];
    unsigned hb0 = __float_as_uint(w0) & 0xFFFF0000u;
    A4h[i] = (short)(hb0 >> 16);
    A5l[i] = (i < 4) ? bf16hi(w0 - __uint_as_float(hb0)) : (short)0;
    // post-layer A: row 0 only, h1 plane only (i>=4)
    float wpv = (b == 0 && i >= 4) ? KSC * Wihp[r] : 0.0f;
    Ap[i] = bf16hi(wpv);
  }

  // --- per-row constants (rows q*4..q*4+3), all KSC-scaled ---
  float4v c1v, c0pv, a0pv;
#pragma unroll
  for (int r = 0; r < 4; ++r) {
    const int row = q * 4 + r;
    c1v[r] = KSC * (bih1[row] + bhh1[row]);
    float a0w = Wih0[row];  // IN=1: Wih0 is (16,1)
    a0pv[r] = KSC * 0.5f * a0w;
    c0pv[r] = KSC * __builtin_fmaf(0.5f, a0w, bih0[row] + bhh0[row]);
  }
  const float whp = KSC * Whhp[0];
  float4v cpv = {0.f, 0.f, 0.f, 0.f};
  cpv[0] = (q == 0) ? KSC * (bihp[0] + bhhp[0]) : 0.0f;

  float yv = post_h0[0];
  float yw[16];
#pragma unroll
  for (int s = 0; s < 16; ++s) yw[s] = 0.0f;

  const float* xp = x + (size_t)batch * T_LEN + t0;
  float* ob = out + (size_t)batch * T_LEN + t0;

  // --- init states straight into register B fragments ---
  uint4v B4, B1;
  {
    float4v h0i, h1i;
#pragma unroll
    for (int r = 0; r < 4; ++r) {
      h0i[r] = prev_h0[q * 4 + r];
      h1i[r] = prev_h0[HDIM + q * 4 + r];
    }
    uint2 h0h = pack_hi(h0i);
    uint2 h0l = pack_lo(h0i);
    uint2 h1h = pack_hi(h1i);
    B4 = mk4(h0h, h0l);
    B1 = mk4(h0h, h1h);
  }

  const int NC = trip / 16;
  // x chunk prefetch: each lane loads its own batch's 16 x values
  float4v xA = *(const float4v*)(xp);
  float4v xB = *(const float4v*)(xp + 4);
  float4v xC = *(const float4v*)(xp + 8);
  float4v xD = *(const float4v*)(xp + 12);

  for (int c = 0; c < NC; ++c) {
    float4v x0_ = xA, x1_ = xB, x2_ = xC, x3_ = xD;
    if (c + 1 < NC) {
      const float* xn = xp + (c + 1) * 16;
      xA = *(const float4v*)(xn);
      xB = *(const float4v*)(xn + 4);
      xC = *(const float4v*)(xn + 8);
      xD = *(const float4v*)(xn + 12);
    }

#pragma unroll
    for (int i = 0; i < 16; ++i) {
      // flush chunk c-1's y (slots complete after (c, i=1))
      if (i == 2) {
        if (c > wchunks && q == 0) {
#pragma unroll
          for (int r = 0; r < 4; ++r) {
            float4v v = {yw[r * 4], yw[r * 4 + 1], yw[r * 4 + 2],
                         yw[r * 4 + 3]};
            *(float4v*)(ob + (c - 1) * 16 + r * 4) = v;
          }
        }
      }

      const bool first = (c == 0 && i == 0);
      float xcur = (i < 4)    ? x0_[i & 3]
                   : (i < 8)  ? x1_[i & 3]
                   : (i < 12) ? x2_[i & 3]
                              : x3_[i & 3];
      float4v cx;
#pragma unroll
      for (int r = 0; r < 4; ++r)
        cx[r] = __builtin_fmaf(a0pv[r], xcur, c0pv[r]);

      // 5 MFMAs off B1/B4 = [h0_{t-1}; h1_{t-2}] planes (skewed pipeline)
      short8 B1s = as_s8(B1);
      short8 B4s = as_s8(B4);
      float4v d1 = MFMA(A1h, B1s, c1v);  // W1hi . h(bf16)
      d1 = MFMA(A1l, B1s, d1);           // + W1lo . h
      float4v dp = MFMA(Ap, B1s, cpv);   // row0: wp . h1_{t-2} + cp
      float4v d0 = MFMA(A4h, B4s, cx);   // W0hi.(h0hi+h0lo) + bias + x
      d0 = MFMA(A5l, B4s, d0);           // + W0lo.h0hi

      float4v hn1, hn0;
#pragma unroll
      for (int r = 0; r < 4; ++r) {
        hn1[r] = tanh_pre(d1[r]);  // h1_{t-1}
        hn0[r] = tanh_pre(d0[r]);  // h0_t
      }

      // y_{t-2} on q==0 lanes (garbage elsewhere, harmless)
      float yn = tanh_pre(__builtin_fmaf(whp, yv, dp[0]));
      if (i >= 2) {
        yv = yn;
      } else {
        if (c > 0) yv = yn;  // t<2: keep init y
      }
      yw[(i + 14) & 15] = yv;

      // next-step B fragments built entirely in-lane (sigma layout)
      uint2 h0h = pack_hi(hn0);
      uint2 h0l = pack_lo(hn0);
      B4 = mk4(h0h, h0l);
      if (!first) {
        uint2 h1h = pack_hi(hn1);
        B1 = mk4(h0h, h1h);
      } else {
        B1[0] = h0h.x;  // h1 half keeps init at t=0
        B1[1] = h0h.y;
      }
    }
  }

  // --- drain: y_{trip-2}, y_{trip-1}, then flush last chunk ---
  {
    // B1 = [h0_{trip-1}; h1_{trip-2}]
    short8 B1s = as_s8(B1);
    float4v d1 = MFMA(A1h, B1s, c1v);
    d1 = MFMA(A1l, B1s, d1);
    float4v dp = MFMA(Ap, B1s, cpv);
    float4v hn1;
#pragma unroll
    for (int r = 0; r < 4; ++r) hn1[r] = tanh_pre(d1[r]);  // h1_{trip-1}
    yv = tanh_pre(__builtin_fmaf(whp, yv, dp[0]));         // y_{trip-2}
    yw[14] = yv;
    uint2 h1h = pack_hi(hn1);
    B1[2] = h1h.x;
    B1[3] = h1h.y;
    B1s = as_s8(B1);
    dp = MFMA(Ap, B1s, cpv);
    yv = tanh_pre(__builtin_fmaf(whp, yv, dp[0]));  // y_{trip-1}
    yw[15] = yv;
    if (q == 0) {
#pragma unroll
      for (int r = 0; r < 4; ++r) {
        float4v v = {yw[r * 4], yw[r * 4 + 1], yw[r * 4 + 2], yw[r * 4 + 3]};
        *(float4v*)(ob + (NC - 1) * 16 + r * 4) = v;
      }
    }
  }
}

extern "C" void kernel_launch(void* const* d_in, const int* in_sizes, int n_in,
                              void* d_out, int out_size, void* d_ws,
                              size_t ws_size, hipStream_t stream) {
  const float* x = (const float*)d_in[0];
  const float* prev_h0 = (const float*)d_in[1];
  const float* post_h0 = (const float*)d_in[2];
  const float* Wih0 = (const float*)d_in[3];
  const float* Whh0 = (const float*)d_in[4];
  const float* bih0 = (const float*)d_in[5];
  const float* bhh0 = (const float*)d_in[6];
  const float* Wih1 = (const float*)d_in[7];
  const float* Whh1 = (const float*)d_in[8];
  const float* bih1 = (const float*)d_in[9];
  const float* bhh1 = (const float*)d_in[10];
  const float* Wihp = (const float*)d_in[11];
  const float* Whhp = (const float*)d_in[12];
  const float* bihp = (const float*)d_in[13];
  const float* bhhp = (const float*)d_in[14];
  float* out = (float*)d_out;

  // 16 batch-groups x 32 segment-quads = 512 blocks x 256 threads
  // = 2048 waves = 2 waves/SIMD (2 blocks/CU, 0 LDS)
  rnn3_kernel<<<dim3(512), dim3(256), 0, stream>>>(
      x, prev_h0, post_h0, Wih0, Whh0, bih0, bhh0, Wih1, Whh1, bih1, bhh1,
      Wihp, Whhp, bihp, bhhp, out);
}